// Round 2
// baseline (641.763 us; speedup 1.0000x reference)
//
#include <hip/hip_runtime.h>

typedef __attribute__((ext_vector_type(8))) short short8;
typedef __attribute__((ext_vector_type(4))) short short4v;
typedef __attribute__((ext_vector_type(4))) float f32x4;

#define ASYNC16(g, l) __builtin_amdgcn_global_load_lds( \
    (__attribute__((address_space(1))) void*)(g), \
    (__attribute__((address_space(3))) void*)(l), 16, 0, 0)

__device__ __forceinline__ short f2bf(float f) {
  union { float f; unsigned u; } v; v.f = f;
  unsigned r = v.u + 0x7fffu + ((v.u >> 16) & 1u);
  return (short)(r >> 16);
}

// pack 2 floats -> 2 bf16 in one dword (round-half-up), lo in low 16
__device__ __forceinline__ unsigned pack_bf2(float lo, float hi) {
  union { float f; unsigned u; } a, b; a.f = lo; b.f = hi;
  return __builtin_amdgcn_perm(b.u + 0x8000u, a.u + 0x8000u, 0x07060302u);
}

__device__ __forceinline__ f32x4 fzero4() {
  f32x4 z; z[0] = 0.f; z[1] = 0.f; z[2] = 0.f; z[3] = 0.f; return z;
}

// ---------- fp32 -> bf16 conversion of x1, x2, Wq, Wk, Wv, Wo ----------
__global__ __launch_bounds__(256) void cvt_all(
    const float* __restrict__ x1, const float* __restrict__ x2,
    const float* __restrict__ wq, const float* __restrict__ wk,
    const float* __restrict__ wv, const float* __restrict__ wo,
    short* __restrict__ dst) {
  long e = ((long)blockIdx.x * 256 + threadIdx.x) * 4;
  const float* src; long loc;
  if (e < 4194304L)       { src = x1; loc = e; }
  else if (e < 12582912L) { src = x2; loc = e - 4194304L; }
  else if (e < 13631488L) { src = wq; loc = e - 12582912L; }
  else if (e < 14680064L) { src = wk; loc = e - 13631488L; }
  else if (e < 15728640L) { src = wv; loc = e - 14680064L; }
  else                    { src = wo; loc = e - 15728640L; }
  float4 v = *(const float4*)(src + loc);
  short4v o;
  o[0] = f2bf(v.x); o[1] = f2bf(v.y); o[2] = f2bf(v.z); o[3] = f2bf(v.w);
  *(short4v*)(dst + e) = o;
}

// ---------- fused Q/K/V projection GEMM (m97-style staging) ----------
// grid (8, 160): y<32 -> Q rows (M=4096), y in [32,96) -> K (M=8192), else V
// C = A @ W^T + bias; 128x128 tile, BK=32, global_load_lds width-16 staging.
__global__ __launch_bounds__(256) void proj(
    const short* __restrict__ xb1, const short* __restrict__ xb2,
    const short* __restrict__ wqp, const short* __restrict__ wkp, const short* __restrict__ wvp,
    const float* __restrict__ bq, const float* __restrict__ bk, const float* __restrict__ bv,
    short* __restrict__ qb, short* __restrict__ kb, short* __restrict__ vb) {
  __shared__ short As[128 * 32];
  __shared__ short Bs[128 * 32];
  const int tid = threadIdx.x, w = tid >> 6, lane = tid & 63;
  const int quad = lane >> 4, col = lane & 15;
  const int waveM = (w >> 1) * 64, waveN = (w & 1) * 64;
  const int my = blockIdx.y, bn = blockIdx.x * 128;
  const short* A; const short* W; const float* bias; int mode, bm;
  if (my < 32)      { A = xb1; W = wqp; bias = bq; mode = 0; bm = my * 128; }
  else if (my < 96) { A = xb2; W = wkp; bias = bk; mode = 1; bm = (my - 32) * 128; }
  else              { A = xb2; W = wvp; bias = bv; mode = 2; bm = (my - 96) * 128; }

  f32x4 acc[4][4];
  for (int mi = 0; mi < 4; ++mi)
    for (int ni = 0; ni < 4; ++ni)
      acc[mi][ni] = fzero4();

  const int srow = w * 16 + (lane >> 2), scol = (lane & 3) * 8;
  const short* ga = A + (size_t)(bm + srow) * 1024 + scol;
  const short* gb = W + (size_t)(bn + srow) * 1024 + scol;
  short* lA = As + w * 512;   // wave-uniform LDS base; HW deposits at base + lane*16B
  short* lB = Bs + w * 512;

  for (int kk = 0; kk < 1024; kk += 32) {
    __syncthreads();  // prior frag reads done before overwrite
    ASYNC16(ga + kk,         lA);
    ASYNC16(ga + kk + 65536, lA + 2048);  // rows +64
    ASYNC16(gb + kk,         lB);
    ASYNC16(gb + kk + 65536, lB + 2048);
    __syncthreads();  // drains vmcnt(0): LDS tiles ready
    short8 af[4], bf[4];
    for (int mi = 0; mi < 4; ++mi)
      af[mi] = *(const short8*)(As + (waveM + mi * 16 + col) * 32 + quad * 8);
    for (int ni = 0; ni < 4; ++ni)
      bf[ni] = *(const short8*)(Bs + (waveN + ni * 16 + col) * 32 + quad * 8);
    for (int mi = 0; mi < 4; ++mi)
      for (int ni = 0; ni < 4; ++ni)
        acc[mi][ni] = __builtin_amdgcn_mfma_f32_16x16x32_bf16(af[mi], bf[ni], acc[mi][ni], 0, 0, 0);
  }

  for (int ni = 0; ni < 4; ++ni) {
    int n = bn + waveN + ni * 16 + col;
    float bvl = bias[n];
    int hh = n >> 6, dd = n & 63;
    for (int mi = 0; mi < 4; ++mi) {
      int m0 = bm + waveM + mi * 16 + quad * 4;
      for (int r = 0; r < 4; ++r) {
        float val = acc[mi][ni][r] + bvl;
        int m = m0 + r;
        if (mode == 0) {         // q: [b*16+h][s][64], S=1024
          int bb = m >> 10, s = m & 1023;
          qb[(((size_t)(bb * 16 + hh)) * 1024 + s) * 64 + dd] = f2bf(val);
        } else if (mode == 1) {  // k: [b*16+h][s][64], S=2048
          int bb = m >> 11, s = m & 2047;
          kb[(((size_t)(bb * 16 + hh)) * 2048 + s) * 64 + dd] = f2bf(val);
        } else {                 // v: tiled transposed [bh][kt][d][kv'], kv' = (kv%16)*4 + kv/16
          int bb = m >> 11, s = m & 2047;
          int kt = s >> 6, kvin = s & 63;
          int kvp = ((kvin & 15) << 2) | (kvin >> 4);
          vb[((((size_t)(bb * 16 + hh)) * 32 + kt) * 64 + dd) * 64 + kvp] = f2bf(val);
        }
      }
    }
  }
}

// ---------- output GEMM: out[4096,1024] fp32 = ob @ Wo^T + bo ----------
__global__ __launch_bounds__(256) void out_gemm(
    const short* __restrict__ A, const short* __restrict__ W,
    const float* __restrict__ bias, float* __restrict__ out) {
  __shared__ short As[128 * 32];
  __shared__ short Bs[128 * 32];
  const int tid = threadIdx.x, w = tid >> 6, lane = tid & 63;
  const int quad = lane >> 4, col = lane & 15;
  const int waveM = (w >> 1) * 64, waveN = (w & 1) * 64;
  const int bn = blockIdx.x * 128, bm = blockIdx.y * 128;

  f32x4 acc[4][4];
  for (int mi = 0; mi < 4; ++mi)
    for (int ni = 0; ni < 4; ++ni)
      acc[mi][ni] = fzero4();

  const int srow = w * 16 + (lane >> 2), scol = (lane & 3) * 8;
  const short* ga = A + (size_t)(bm + srow) * 1024 + scol;
  const short* gb = W + (size_t)(bn + srow) * 1024 + scol;
  short* lA = As + w * 512;
  short* lB = Bs + w * 512;

  for (int kk = 0; kk < 1024; kk += 32) {
    __syncthreads();
    ASYNC16(ga + kk,         lA);
    ASYNC16(ga + kk + 65536, lA + 2048);
    ASYNC16(gb + kk,         lB);
    ASYNC16(gb + kk + 65536, lB + 2048);
    __syncthreads();
    short8 af[4], bf[4];
    for (int mi = 0; mi < 4; ++mi)
      af[mi] = *(const short8*)(As + (waveM + mi * 16 + col) * 32 + quad * 8);
    for (int ni = 0; ni < 4; ++ni)
      bf[ni] = *(const short8*)(Bs + (waveN + ni * 16 + col) * 32 + quad * 8);
    for (int mi = 0; mi < 4; ++mi)
      for (int ni = 0; ni < 4; ++ni)
        acc[mi][ni] = __builtin_amdgcn_mfma_f32_16x16x32_bf16(af[mi], bf[ni], acc[mi][ni], 0, 0, 0);
  }

  for (int ni = 0; ni < 4; ++ni) {
    int n = bn + waveN + ni * 16 + col;
    float bvl = bias[n];
    for (int mi = 0; mi < 4; ++mi) {
      int m0 = bm + waveM + mi * 16 + quad * 4;
      for (int r = 0; r < 4; ++r)
        out[(size_t)(m0 + r) * 1024 + n] = acc[mi][ni][r] + bvl;
    }
  }
}

// ---------- flash attention, no-max softmax ----------
// q [bh][1024][64]; k [bh][2048][64]; v tiled [bh][32][64 d][64 kv'] -> O bf16 [4096][1024]
// grid 512: blockIdx.x = bh*8 + qt (128-row Q tile); block 256, wave = 32 q-rows
__global__ __launch_bounds__(256) void attn(
    const short* __restrict__ Q, const short* __restrict__ K,
    const short* __restrict__ V, short* __restrict__ O) {
  __shared__ short Ks[64][72];
  __shared__ short Vs[64][72];
  __shared__ short Ps[128][72];
  const int tid = threadIdx.x, w = tid >> 6, lane = tid & 63;
  const int quad = lane >> 4, col = lane & 15;
  const int bh = blockIdx.x >> 3, qt = blockIdx.x & 7;
  const int b = bh >> 4, h = bh & 15;
  const int qbase = w * 32;

  const short* qp = Q + ((size_t)bh * 1024 + qt * 128) * 64;
  const short* kp = K + (size_t)bh * 131072;
  const short* vp = V + (size_t)bh * 131072;

  // Q A-frags straight from global (wave-private rows), held in registers all loop
  short8 aq[2][2];
  for (int mi = 0; mi < 2; ++mi) {
    const short* qr = qp + (qbase + mi * 16 + col) * 64 + quad * 8;
    aq[mi][0] = *(const short8*)qr;
    aq[mi][1] = *(const short8*)(qr + 32);
  }

  float lsum[2][4];
  f32x4 oa[2][4];
  for (int mi = 0; mi < 2; ++mi) {
    for (int r = 0; r < 4; ++r) lsum[mi][r] = 0.f;
    for (int ni = 0; ni < 4; ++ni) oa[mi][ni] = fzero4();
  }

  const int strow = tid >> 2, stc = (tid & 3) * 16;
  const float c = 0.18033688011112042f;  // log2(e)/8: p = 2^(s*c) = e^(s/8)

  for (int kt = 0; kt < 32; ++kt) {
    const short* kg = kp + kt * 4096 + tid * 16;
    const short* vg = vp + kt * 4096 + tid * 16;
    short8 k0 = *(const short8*)kg, k1 = *(const short8*)(kg + 8);
    short8 v0 = *(const short8*)vg, v1 = *(const short8*)(vg + 8);
    __syncthreads();  // prior tile's LDS reads complete
    *(short8*)&Ks[strow][stc]     = k0;
    *(short8*)&Ks[strow][stc + 8] = k1;
    *(short8*)&Vs[strow][stc]     = v0;
    *(short8*)&Vs[strow][stc + 8] = v1;
    __syncthreads();

    // S = Q K^T
    short8 bk0[4], bk1[4];
    for (int nk = 0; nk < 4; ++nk) {
      bk0[nk] = *(const short8*)&Ks[nk * 16 + col][quad * 8];
      bk1[nk] = *(const short8*)&Ks[nk * 16 + col][32 + quad * 8];
    }
    f32x4 sf[2][4];
    for (int mi = 0; mi < 2; ++mi)
      for (int nk = 0; nk < 4; ++nk) {
        f32x4 z = fzero4();
        z = __builtin_amdgcn_mfma_f32_16x16x32_bf16(aq[mi][0], bk0[nk], z, 0, 0, 0);
        z = __builtin_amdgcn_mfma_f32_16x16x32_bf16(aq[mi][1], bk1[nk], z, 0, 0, 0);
        sf[mi][nk] = z;
      }

    // p = exp(s/8), no max subtraction (scores bounded); per-lane row-sum accum
    for (int mi = 0; mi < 2; ++mi)
      for (int nk = 0; nk < 4; ++nk)
        for (int r = 0; r < 4; ++r)
          sf[mi][nk][r] = __builtin_amdgcn_exp2f(sf[mi][nk][r] * c);
    for (int mi = 0; mi < 2; ++mi)
      for (int r = 0; r < 4; ++r)
        lsum[mi][r] += (sf[mi][0][r] + sf[mi][1][r]) + (sf[mi][2][r] + sf[mi][3][r]);

    // P -> LDS: lane's 4 same-row values are kv' = col*4 + nk (contiguous) -> packed b64
    for (int mi = 0; mi < 2; ++mi)
      for (int r = 0; r < 4; ++r) {
        uint2 d;
        d.x = pack_bf2(sf[mi][0][r], sf[mi][1][r]);
        d.y = pack_bf2(sf[mi][2][r], sf[mi][3][r]);
        *(uint2*)&Ps[qbase + mi * 16 + quad * 4 + r][col * 4] = d;
      }
    // no barrier: each wave reads only its own Ps rows

    // O += P V   (Vs already [d][kv'] in matching permuted order)
    short8 bv0[4], bv1[4];
    for (int ni = 0; ni < 4; ++ni) {
      bv0[ni] = *(const short8*)&Vs[ni * 16 + col][quad * 8];
      bv1[ni] = *(const short8*)&Vs[ni * 16 + col][32 + quad * 8];
    }
    for (int mi = 0; mi < 2; ++mi) {
      short8 ap0 = *(const short8*)&Ps[qbase + mi * 16 + col][quad * 8];
      short8 ap1 = *(const short8*)&Ps[qbase + mi * 16 + col][32 + quad * 8];
      for (int ni = 0; ni < 4; ++ni) {
        oa[mi][ni] = __builtin_amdgcn_mfma_f32_16x16x32_bf16(ap0, bv0[ni], oa[mi][ni], 0, 0, 0);
        oa[mi][ni] = __builtin_amdgcn_mfma_f32_16x16x32_bf16(ap1, bv1[ni], oa[mi][ni], 0, 0, 0);
      }
    }
  }

  // final row-sum reduce across the 16 col-lanes, then normalize + write
  for (int mi = 0; mi < 2; ++mi)
    for (int r = 0; r < 4; ++r) {
      float s = lsum[mi][r];
      s += __shfl_xor(s, 1);
      s += __shfl_xor(s, 2);
      s += __shfl_xor(s, 4);
      s += __shfl_xor(s, 8);
      lsum[mi][r] = 1.f / s;
    }
  for (int mi = 0; mi < 2; ++mi) {
    size_t row0 = (size_t)b * 1024 + qt * 128 + qbase + mi * 16 + quad * 4;
    for (int ni = 0; ni < 4; ++ni) {
      int cg = h * 64 + ni * 16 + col;
      for (int r = 0; r < 4; ++r)
        O[(row0 + r) * 1024 + cg] = f2bf(oa[mi][ni][r] * lsum[mi][r]);
    }
  }
}

// ---------- launcher ----------
extern "C" void kernel_launch(void* const* d_in, const int* in_sizes, int n_in,
                              void* d_out, int out_size, void* d_ws, size_t ws_size,
                              hipStream_t stream) {
  const float* x1 = (const float*)d_in[0];
  const float* x2 = (const float*)d_in[1];
  const float* Wq = (const float*)d_in[2];
  const float* bq = (const float*)d_in[3];
  const float* Wk = (const float*)d_in[4];
  const float* bk = (const float*)d_in[5];
  const float* Wv = (const float*)d_in[6];
  const float* bv = (const float*)d_in[7];
  const float* Wo = (const float*)d_in[8];
  const float* bo = (const float*)d_in[9];

  char* ws = (char*)d_ws;
  short* xb1 = (short*)(ws + 0);         // x1 bf16, 8 MB
  short* xb2 = (short*)(ws + 8388608);   // x2 bf16, 16 MB
  short* wqb = (short*)(ws + 25165824);  // Wq bf16, 2 MB
  short* wkb = (short*)(ws + 27262976);
  short* wvb = (short*)(ws + 29360128);
  short* wob = (short*)(ws + 31457280);
  short* qb  = (short*)(ws + 33554432);  // q [bh][1024][64] bf16, 8 MB
  short* kb  = (short*)(ws + 41943040);  // k [bh][2048][64] bf16, 16 MB
  short* vb  = (short*)(ws + 58720256);  // v tiled [bh][32][64][64] bf16, 16 MB
  short* ob  = (short*)(ws + 75497472);  // attn out [4096][1024] bf16, 8 MB

  cvt_all<<<16384, 256, 0, stream>>>(x1, x2, Wq, Wk, Wv, Wo, (short*)ws);
  proj<<<dim3(8, 160), 256, 0, stream>>>(xb1, xb2, wqb, wkb, wvb, bq, bk, bv, qb, kb, vb);
  attn<<<512, 256, 0, stream>>>(qb, kb, vb, ob);
  out_gemm<<<dim3(8, 32), 256, 0, stream>>>(ob, wob, bo, (float*)d_out);
}

// Round 3
// 241.650 us; speedup vs baseline: 2.6558x; 2.6558x over previous
//
#include <hip/hip_runtime.h>

typedef __attribute__((ext_vector_type(8))) short short8;
typedef __attribute__((ext_vector_type(4))) short short4v;
typedef __attribute__((ext_vector_type(4))) float f32x4;

#define ASYNC16(g, l) __builtin_amdgcn_global_load_lds( \
    (__attribute__((address_space(1))) void*)(g), \
    (__attribute__((address_space(3))) void*)(l), 16, 0, 0)

__device__ __forceinline__ short f2bf(float f) {
  union { float f; unsigned u; } v; v.f = f;
  unsigned r = v.u + 0x7fffu + ((v.u >> 16) & 1u);
  return (short)(r >> 16);
}

// pack 2 floats -> 2 bf16 in one dword (round-half-up), lo in low 16
__device__ __forceinline__ unsigned pack_bf2(float lo, float hi) {
  union { float f; unsigned u; } a, b; a.f = lo; b.f = hi;
  return __builtin_amdgcn_perm(b.u + 0x8000u, a.u + 0x8000u, 0x07060302u);
}

__device__ __forceinline__ f32x4 fzero4() {
  f32x4 z; z[0] = 0.f; z[1] = 0.f; z[2] = 0.f; z[3] = 0.f; return z;
}

// barrier that does NOT drain vmcnt: in-flight register prefetch loads survive.
// lgkmcnt(0) makes this wave's LDS writes visible before the barrier.
__device__ __forceinline__ void wg_barrier() {
  asm volatile("s_waitcnt lgkmcnt(0)\n\ts_barrier" ::: "memory");
}

// ---------- fp32 -> bf16 conversion of x1, x2, Wq, Wk, Wv, Wo ----------
__global__ __launch_bounds__(256) void cvt_all(
    const float* __restrict__ x1, const float* __restrict__ x2,
    const float* __restrict__ wq, const float* __restrict__ wk,
    const float* __restrict__ wv, const float* __restrict__ wo,
    short* __restrict__ dst) {
  long e = ((long)blockIdx.x * 256 + threadIdx.x) * 4;
  const float* src; long loc;
  if (e < 4194304L)       { src = x1; loc = e; }
  else if (e < 12582912L) { src = x2; loc = e - 4194304L; }
  else if (e < 13631488L) { src = wq; loc = e - 12582912L; }
  else if (e < 14680064L) { src = wk; loc = e - 13631488L; }
  else if (e < 15728640L) { src = wv; loc = e - 14680064L; }
  else                    { src = wo; loc = e - 15728640L; }
  float4 v = *(const float4*)(src + loc);
  short4v o;
  o[0] = f2bf(v.x); o[1] = f2bf(v.y); o[2] = f2bf(v.z); o[3] = f2bf(v.w);
  *(short4v*)(dst + e) = o;
}

// ---------- fused Q/K/V projection GEMM ----------
// grid (160, 8): x = m-panel (Q 0..31 | K 32..95 | V 96..159), y = n-panel.
// Same-A blocks share XCD (flat stride 160 % 8 == 0). Epilogue: LDS bounce -> coalesced.
__global__ __launch_bounds__(256) void proj(
    const short* __restrict__ xb1, const short* __restrict__ xb2,
    const short* __restrict__ wqp, const short* __restrict__ wkp, const short* __restrict__ wvp,
    const float* __restrict__ bq, const float* __restrict__ bk, const float* __restrict__ bv,
    short* __restrict__ qb, short* __restrict__ kb, short* __restrict__ vb) {
  __shared__ short smem[16384];           // loop: As=smem[0:4096], Bs=smem[4096:8192]; epilogue: 128x128 C tile
  short* As = smem;
  short* Bs = smem + 4096;
  const int tid = threadIdx.x, w = tid >> 6, lane = tid & 63;
  const int quad = lane >> 4, col = lane & 15;
  const int waveM = (w >> 1) * 64, waveN = (w & 1) * 64;
  const int my = blockIdx.x, bn = blockIdx.y * 128;
  const short* A; const short* W; const float* bias; int mode, bm;
  if (my < 32)      { A = xb1; W = wqp; bias = bq; mode = 0; bm = my * 128; }
  else if (my < 96) { A = xb2; W = wkp; bias = bk; mode = 1; bm = (my - 32) * 128; }
  else              { A = xb2; W = wvp; bias = bv; mode = 2; bm = (my - 96) * 128; }

  f32x4 acc[4][4];
  for (int mi = 0; mi < 4; ++mi)
    for (int ni = 0; ni < 4; ++ni)
      acc[mi][ni] = fzero4();

  const int srow = w * 16 + (lane >> 2), scol = (lane & 3) * 8;
  const short* ga = A + (size_t)(bm + srow) * 1024 + scol;
  const short* gb = W + (size_t)(bn + srow) * 1024 + scol;
  short* lA = As + w * 512;   // wave-uniform LDS base; HW deposits at base + lane*16B
  short* lB = Bs + w * 512;

  for (int kk = 0; kk < 1024; kk += 32) {
    __syncthreads();
    ASYNC16(ga + kk,         lA);
    ASYNC16(ga + kk + 65536, lA + 2048);  // rows +64
    ASYNC16(gb + kk,         lB);
    ASYNC16(gb + kk + 65536, lB + 2048);
    __syncthreads();  // drains vmcnt(0): LDS tiles ready
    short8 af[4], bf[4];
    for (int mi = 0; mi < 4; ++mi)
      af[mi] = *(const short8*)(As + (waveM + mi * 16 + col) * 32 + quad * 8);
    for (int ni = 0; ni < 4; ++ni)
      bf[ni] = *(const short8*)(Bs + (waveN + ni * 16 + col) * 32 + quad * 8);
    for (int mi = 0; mi < 4; ++mi)
      for (int ni = 0; ni < 4; ++ni)
        acc[mi][ni] = __builtin_amdgcn_mfma_f32_16x16x32_bf16(af[mi], bf[ni], acc[mi][ni], 0, 0, 0);
  }

  // ---- epilogue: scatter C (bf16, +bias) into swizzled LDS tile, read back coalesced ----
  __syncthreads();  // frag reads done; safe to overwrite As/Bs region
  for (int ni = 0; ni < 4; ++ni) {
    int nn = waveN + ni * 16 + col;
    float bvl = bias[bn + nn];
    for (int mi = 0; mi < 4; ++mi) {
      int m0 = waveM + mi * 16 + quad * 4;
      for (int r = 0; r < 4; ++r) {
        int m = m0 + r;
        smem[m * 128 + (nn ^ ((m & 15) << 3))] = f2bf(acc[mi][ni][r] + bvl);
      }
    }
  }
  __syncthreads();
  if (mode < 2) {
    const int S = (mode == 0) ? 1024 : 2048;
    short* outp = (mode == 0) ? qb : kb;
    const int bb = bm / S, s0 = bm & (S - 1), h0 = bn >> 6;
    for (int it = 0; it < 8; ++it) {
      int f = (it * 256 + tid) * 8;
      int hh = f >> 13, rem = f & 8191, m = rem >> 6, d = rem & 63;
      int nn = hh * 64 + d;
      short8 val = *(const short8*)&smem[m * 128 + (nn ^ ((m & 15) << 3))];
      *(short8*)(outp + ((((size_t)(bb * 16 + h0 + hh)) * S + s0 + m) * 64 + d)) = val;
    }
  } else {
    // v tiled transposed: [bh][kt][d][kv'], kv' = (kv%16)*4 + kv/16
    const int bb = bm >> 11, s0 = bm & 2047, kt0 = s0 >> 6, h0 = bn >> 6;
    for (int it = 0; it < 8; ++it) {
      int f = (it * 256 + tid) * 8;
      int hh = f >> 13, rem = f & 8191, ktl = rem >> 12, r3 = rem & 4095;
      int d = r3 >> 6, kvp0 = r3 & 63;
      int nn = hh * 64 + d;
      short8 val;
      for (int j = 0; j < 8; ++j) {
        int kvp = kvp0 + j;
        int kv = ((kvp & 3) << 4) | (kvp >> 2);
        int m = ktl * 64 + kv;
        val[j] = smem[m * 128 + (nn ^ ((m & 15) << 3))];
      }
      *(short8*)(vb + ((((size_t)(bb * 16 + h0 + hh)) * 32 + (kt0 + ktl)) * 4096) + d * 64 + kvp0) = val;
    }
  }
}

// ---------- output GEMM: out[4096,1024] fp32 = ob @ Wo^T + bo ----------
// grid (32, 8): same-A blocks share XCD. Register-prefetch staging, raw barriers.
__global__ __launch_bounds__(256) void out_gemm(
    const short* __restrict__ A, const short* __restrict__ W,
    const float* __restrict__ bias, float* __restrict__ out) {
  __shared__ short As[4096];
  __shared__ short Bs[4096];
  const int tid = threadIdx.x, w = tid >> 6, lane = tid & 63;
  const int quad = lane >> 4, col = lane & 15;
  const int waveM = (w >> 1) * 64, waveN = (w & 1) * 64;
  const int bm = blockIdx.x * 128, bn = blockIdx.y * 128;

  f32x4 acc[4][4];
  for (int mi = 0; mi < 4; ++mi)
    for (int ni = 0; ni < 4; ++ni)
      acc[mi][ni] = fzero4();

  const int srow = tid >> 1, sc0 = (tid & 1) * 16;
  const short* ga = A + (size_t)(bm + srow) * 1024 + sc0;
  const short* gb = W + (size_t)(bn + srow) * 1024 + sc0;

  short8 a0 = *(const short8*)ga,       a1 = *(const short8*)(ga + 8);
  short8 b0 = *(const short8*)gb,       b1 = *(const short8*)(gb + 8);

  for (int kk = 0; kk < 1024; kk += 32) {
    wg_barrier();  // prior frag reads done; does not drain prefetch vmcnt
    *(short8*)&As[srow * 32 + sc0]     = a0;
    *(short8*)&As[srow * 32 + sc0 + 8] = a1;
    *(short8*)&Bs[srow * 32 + sc0]     = b0;
    *(short8*)&Bs[srow * 32 + sc0 + 8] = b1;
    int kn = (kk < 992) ? kk + 32 : kk;   // prefetch next K-slab into regs
    a0 = *(const short8*)(ga + kn); a1 = *(const short8*)(ga + kn + 8);
    b0 = *(const short8*)(gb + kn); b1 = *(const short8*)(gb + kn + 8);
    wg_barrier();
    short8 af[4], bf[4];
    for (int mi = 0; mi < 4; ++mi)
      af[mi] = *(const short8*)(As + (waveM + mi * 16 + col) * 32 + quad * 8);
    for (int ni = 0; ni < 4; ++ni)
      bf[ni] = *(const short8*)(Bs + (waveN + ni * 16 + col) * 32 + quad * 8);
    for (int mi = 0; mi < 4; ++mi)
      for (int ni = 0; ni < 4; ++ni)
        acc[mi][ni] = __builtin_amdgcn_mfma_f32_16x16x32_bf16(af[mi], bf[ni], acc[mi][ni], 0, 0, 0);
  }

  for (int ni = 0; ni < 4; ++ni) {
    int n = bn + waveN + ni * 16 + col;
    float bvl = bias[n];
    for (int mi = 0; mi < 4; ++mi) {
      int m0 = bm + waveM + mi * 16 + quad * 4;
      for (int r = 0; r < 4; ++r)
        out[(size_t)(m0 + r) * 1024 + n] = acc[mi][ni][r] + bvl;   // 16 lanes x 4B = full 64B sectors
    }
  }
}

// ---------- flash attention, no-max softmax, register-prefetched K/V ----------
// q [bh][1024][64]; k [bh][2048][64]; v tiled [bh][32][64 d][64 kv'] -> O bf16 [4096][1024]
// grid (64, 8): x = bh (same-bh blocks share XCD for K/V L2 reuse), y = 128-row Q tile.
__global__ __launch_bounds__(256) void attn(
    const short* __restrict__ Q, const short* __restrict__ K,
    const short* __restrict__ V, short* __restrict__ O) {
  __shared__ short Ks[64 * 72];
  __shared__ short Vs[64 * 72];
  __shared__ short Ps[128 * 72];
  const int tid = threadIdx.x, w = tid >> 6, lane = tid & 63;
  const int quad = lane >> 4, col = lane & 15;
  const int bh = blockIdx.x, qt = blockIdx.y;
  const int b = bh >> 4, h = bh & 15;
  const int qbase = w * 32;

  const short* qp = Q + ((size_t)bh * 1024 + qt * 128) * 64;
  const short* kp = K + (size_t)bh * 131072;
  const short* vp = V + (size_t)bh * 131072;

  // Q A-frags straight from global (wave-private rows), held in registers
  short8 aq[2][2];
  for (int mi = 0; mi < 2; ++mi) {
    const short* qr = qp + (qbase + mi * 16 + col) * 64 + quad * 8;
    aq[mi][0] = *(const short8*)qr;
    aq[mi][1] = *(const short8*)(qr + 32);
  }

  float lsum[2][4];
  f32x4 oa[2][4];
  for (int mi = 0; mi < 2; ++mi) {
    for (int r = 0; r < 4; ++r) lsum[mi][r] = 0.f;
    for (int ni = 0; ni < 4; ++ni) oa[mi][ni] = fzero4();
  }

  const int sr = tid >> 2, sc0 = (tid & 3) * 16;
  const float c = 0.18033688011112042f;  // log2(e)/8

  // prefetch tile 0 into regs
  short8 k0 = *(const short8*)(kp + tid * 16), k1 = *(const short8*)(kp + tid * 16 + 8);
  short8 v0 = *(const short8*)(vp + tid * 16), v1 = *(const short8*)(vp + tid * 16 + 8);

  for (int kt = 0; kt < 32; ++kt) {
    wg_barrier();  // prior tile's LDS reads complete (no vmcnt drain)
    *(short8*)&Ks[sr * 72 + sc0]     = k0;
    *(short8*)&Ks[sr * 72 + sc0 + 8] = k1;
    *(short8*)&Vs[sr * 72 + sc0]     = v0;
    *(short8*)&Vs[sr * 72 + sc0 + 8] = v1;
    {  // issue next tile's loads now; latency hides under this tile's compute
      int ktn = (kt < 31) ? kt + 1 : kt;
      const short* kg = kp + ktn * 4096 + tid * 16;
      const short* vg = vp + ktn * 4096 + tid * 16;
      k0 = *(const short8*)kg; k1 = *(const short8*)(kg + 8);
      v0 = *(const short8*)vg; v1 = *(const short8*)(vg + 8);
    }
    wg_barrier();

    // S = Q K^T
    short8 bk0[4], bk1[4];
    for (int nk = 0; nk < 4; ++nk) {
      bk0[nk] = *(const short8*)&Ks[(nk * 16 + col) * 72 + quad * 8];
      bk1[nk] = *(const short8*)&Ks[(nk * 16 + col) * 72 + 32 + quad * 8];
    }
    f32x4 sf[2][4];
    for (int mi = 0; mi < 2; ++mi)
      for (int nk = 0; nk < 4; ++nk) {
        f32x4 z = fzero4();
        z = __builtin_amdgcn_mfma_f32_16x16x32_bf16(aq[mi][0], bk0[nk], z, 0, 0, 0);
        z = __builtin_amdgcn_mfma_f32_16x16x32_bf16(aq[mi][1], bk1[nk], z, 0, 0, 0);
        sf[mi][nk] = z;
      }

    // p = exp(s/8) (scores bounded, softmax shift-invariant); per-lane row-sums
    for (int mi = 0; mi < 2; ++mi)
      for (int nk = 0; nk < 4; ++nk)
        for (int r = 0; r < 4; ++r)
          sf[mi][nk][r] = __builtin_amdgcn_exp2f(sf[mi][nk][r] * c);
    for (int mi = 0; mi < 2; ++mi)
      for (int r = 0; r < 4; ++r)
        lsum[mi][r] += (sf[mi][0][r] + sf[mi][1][r]) + (sf[mi][2][r] + sf[mi][3][r]);

    // P -> LDS: lane's 4 same-row values are kv' = col*4 + nk (contiguous) -> packed b64
    for (int mi = 0; mi < 2; ++mi)
      for (int r = 0; r < 4; ++r) {
        uint2 d;
        d.x = pack_bf2(sf[mi][0][r], sf[mi][1][r]);
        d.y = pack_bf2(sf[mi][2][r], sf[mi][3][r]);
        *(uint2*)&Ps[(qbase + mi * 16 + quad * 4 + r) * 72 + col * 4] = d;
      }
    // no barrier: each wave reads only its own Ps rows

    // O += P V   (Vs is [d][kv'] in matching permuted order)
    short8 bv0[4], bv1[4];
    for (int ni = 0; ni < 4; ++ni) {
      bv0[ni] = *(const short8*)&Vs[(ni * 16 + col) * 72 + quad * 8];
      bv1[ni] = *(const short8*)&Vs[(ni * 16 + col) * 72 + 32 + quad * 8];
    }
    for (int mi = 0; mi < 2; ++mi) {
      short8 ap0 = *(const short8*)&Ps[(qbase + mi * 16 + col) * 72 + quad * 8];
      short8 ap1 = *(const short8*)&Ps[(qbase + mi * 16 + col) * 72 + 32 + quad * 8];
      for (int ni = 0; ni < 4; ++ni) {
        oa[mi][ni] = __builtin_amdgcn_mfma_f32_16x16x32_bf16(ap0, bv0[ni], oa[mi][ni], 0, 0, 0);
        oa[mi][ni] = __builtin_amdgcn_mfma_f32_16x16x32_bf16(ap1, bv1[ni], oa[mi][ni], 0, 0, 0);
      }
    }
  }

  // normalize, then LDS-bounce O for coalesced 16B stores
  for (int mi = 0; mi < 2; ++mi)
    for (int r = 0; r < 4; ++r) {
      float s = lsum[mi][r];
      s += __shfl_xor(s, 1);
      s += __shfl_xor(s, 2);
      s += __shfl_xor(s, 4);
      s += __shfl_xor(s, 8);
      lsum[mi][r] = 1.f / s;
    }
  __syncthreads();
  for (int mi = 0; mi < 2; ++mi)
    for (int ni = 0; ni < 4; ++ni)
      for (int r = 0; r < 4; ++r)
        Ps[(qbase + mi * 16 + quad * 4 + r) * 64 + ni * 16 + col] = f2bf(oa[mi][ni][r] * lsum[mi][r]);
  __syncthreads();
  for (int it = 0; it < 4; ++it) {
    int f = (it * 256 + tid) * 8;      // over [128 q][64 d]
    int q = f >> 6, d = f & 63;
    short8 val = *(const short8*)&Ps[q * 64 + d];
    *(short8*)(O + ((size_t)(b * 1024 + qt * 128 + q)) * 1024 + h * 64 + d) = val;
  }
}

// ---------- launcher ----------
extern "C" void kernel_launch(void* const* d_in, const int* in_sizes, int n_in,
                              void* d_out, int out_size, void* d_ws, size_t ws_size,
                              hipStream_t stream) {
  const float* x1 = (const float*)d_in[0];
  const float* x2 = (const float*)d_in[1];
  const float* Wq = (const float*)d_in[2];
  const float* bq = (const float*)d_in[3];
  const float* Wk = (const float*)d_in[4];
  const float* bk = (const float*)d_in[5];
  const float* Wv = (const float*)d_in[6];
  const float* bv = (const float*)d_in[7];
  const float* Wo = (const float*)d_in[8];
  const float* bo = (const float*)d_in[9];

  char* ws = (char*)d_ws;
  short* xb1 = (short*)(ws + 0);         // x1 bf16, 8 MB
  short* xb2 = (short*)(ws + 8388608);   // x2 bf16, 16 MB
  short* wqb = (short*)(ws + 25165824);  // Wq bf16, 2 MB
  short* wkb = (short*)(ws + 27262976);
  short* wvb = (short*)(ws + 29360128);
  short* wob = (short*)(ws + 31457280);
  short* qb  = (short*)(ws + 33554432);  // q [bh][1024][64] bf16, 8 MB
  short* kb  = (short*)(ws + 41943040);  // k [bh][2048][64] bf16, 16 MB
  short* vb  = (short*)(ws + 58720256);  // v tiled [bh][32][64][64] bf16, 16 MB
  short* ob  = (short*)(ws + 75497472);  // attn out [4096][1024] bf16, 8 MB

  cvt_all<<<16384, 256, 0, stream>>>(x1, x2, Wq, Wk, Wv, Wo, (short*)ws);
  proj<<<dim3(160, 8), 256, 0, stream>>>(xb1, xb2, wqb, wkb, wvb, bq, bk, bv, qb, kb, vb);
  attn<<<dim3(64, 8), 256, 0, stream>>>(qb, kb, vb, ob);
  out_gemm<<<dim3(32, 8), 256, 0, stream>>>(ob, wob, bo, (float*)d_out);
}